// Round 7
// baseline (1564.806 us; speedup 1.0000x reference)
//
#include <hip/hip_runtime.h>
#include <type_traits>

// GNN27: two-branch diffusion GCN (N=8192, F_IN=11, F1=16, F2=32) + multi-head
// tanh-attention pooling. All fp32. Memory-bound on the two 268MB adjacencies,
// each streamed twice -> 1.07GB unique traffic.
//
// R1-R6 lesson: every structure reading A as parallel row-streams in <=1KB
// pieces (direct, global_load_lds DMA, flat-TLP) plateaus at 0.9-1.9 TB/s
// effective; contiguous copy does 6.3 TB/s and R5's scratch-spill traffic
// sustained 2.9 TB/s. The untested variable is sequential run length. R7:
// each wave reads each A row's K-window as ONE 4-8KB sequential burst, row
// after row. P window lives in LDS (ping-pong 64KB f-halves), split-K with a
// tiny deterministic reduce pass. 2-row groups double-buffered in regs.

constexpr int N = 8192;

// ---------------- kernel 1: P1T = (x @ W1)^T   ([16][N]) ----------------
__global__ void k_dense_in(const float* __restrict__ x0, const float* __restrict__ x1,
                           const float* __restrict__ W0, const float* __restrict__ W1,
                           float* __restrict__ o0, float* __restrict__ o1) {
    const int branch = blockIdx.y;
    const float* __restrict__ x = branch ? x1 : x0;
    const float* __restrict__ W = branch ? W1 : W0;
    float* __restrict__ o = branch ? o1 : o0;
    __shared__ float sW[11 * 16];
    if (threadIdx.x < 176) sW[threadIdx.x] = W[threadIdx.x];
    __syncthreads();
    const int n = blockIdx.x * blockDim.x + threadIdx.x;  // grid.x*256 == N exactly
    float xr[11];
#pragma unroll
    for (int j = 0; j < 11; ++j) xr[j] = x[n * 11 + j];
    float acc[16];
#pragma unroll
    for (int f = 0; f < 16; ++f) acc[f] = 0.f;
#pragma unroll
    for (int j = 0; j < 11; ++j)
#pragma unroll
        for (int f = 0; f < 16; ++f) acc[f] += xr[j] * sW[j * 16 + f];
#pragma unroll
    for (int f = 0; f < 16; ++f) o[f * N + n] = acc[f];  // transposed, coalesced
}

// ---------------- kernel 3: P2T = (H1 @ W2)^T   ([32][N]) ----------------
__global__ void k_dense_mid(const float* __restrict__ h0, const float* __restrict__ h1,
                            const float* __restrict__ W0, const float* __restrict__ W1,
                            float* __restrict__ o0, float* __restrict__ o1) {
    const int branch = blockIdx.y;
    const float* __restrict__ h = branch ? h1 : h0;
    const float* __restrict__ W = branch ? W1 : W0;
    float* __restrict__ o = branch ? o1 : o0;
    __shared__ float sW[16 * 32];
    for (int i = threadIdx.x; i < 512; i += blockDim.x) sW[i] = W[i];
    __syncthreads();
    const int n = blockIdx.x * blockDim.x + threadIdx.x;
    float hr[16];
#pragma unroll
    for (int q = 0; q < 4; ++q)
        *reinterpret_cast<float4*>(&hr[q * 4]) =
            *reinterpret_cast<const float4*>(&h[n * 16 + q * 4]);
    float acc[32];
#pragma unroll
    for (int f = 0; f < 32; ++f) acc[f] = 0.f;
#pragma unroll
    for (int j = 0; j < 16; ++j)
#pragma unroll
        for (int f = 0; f < 32; ++f) acc[f] += hr[j] * sW[j * 32 + f];
#pragma unroll
    for (int f = 0; f < 32; ++f) o[f * N + n] = acc[f];  // transposed, coalesced
}

// -------- kernels 2 & 4: partial H = A @ P over a K-window, seq-burst A -----
// Block = 512 thr = 8 waves. Window W = 32768/F (2048|1024). Each wave owns
// 16 rows as 8 groups of 2; per row the window is read as C=W/256 back-to-back
// 1KB wave bursts -> 8KB|4KB sequential runs. P window staged in LDS as two
// 64KB f-halves, ping-ponged; layout (t,g)-major so compute reads are
// contiguous-per-lane ds_read_b128 (conflict-free). Split-K partials go to
// ws; k_reduce sums them + bias + relu. Groups double-buffered: next group's
// A issued one compute-phase + staging ahead of use.
template <int F>
__global__ __launch_bounds__(512, 2) void k_spmm(
    const float* __restrict__ A0, const float* __restrict__ A1,
    const float* __restrict__ PT0, const float* __restrict__ PT1,
    float* __restrict__ part) {
    constexpr int W = 32768 / F;  // K-window: 2048 | 1024
    constexpr int NS = N / W;     // split-K slices: 4 | 8
    constexpr int C = W / 256;    // 1KB chunks per row window: 8 | 4
    constexpr int G2 = F / 8;     // float4 f-groups per half: 2 | 4
    constexpr int NG = 8;         // 2-row groups per wave -> 16 rows/wave
    constexpr int RPB = 128;      // rows per block = 8 waves * 16

    const int br = blockIdx.y;
    const float* __restrict__ A = br ? A1 : A0;
    const float* __restrict__ PT = br ? PT1 : PT0;
    float* __restrict__ pb = part + (size_t)br * NS * N * F;

    __shared__ float plds[16384];  // 64 KB: one f-half of the P window

    const int tid = threadIdx.x;
    const int lane = tid & 63;
    const int wave = tid >> 6;
    const int rb = blockIdx.x / NS, sl = blockIdx.x % NS;
    const int K0 = sl * W;
    const int wrow0 = rb * RPB + wave * (2 * NG);

    const float* __restrict__ Ab = A + (size_t)wrow0 * N + K0 + 4 * lane;

    auto stage = [&](int half) {
        const float* __restrict__ Ps = PT + (size_t)half * (F / 2) * N + K0;
        for (int idx = tid; idx < (F / 2) * W; idx += 512) {
            const int kk = idx & (W - 1);
            const int fl = idx / W;  // consecutive tid -> consecutive kk: coalesced
            plds[((kk & 3) * G2 + (fl >> 2)) * W + ((kk >> 2) << 2) + (fl & 3)] =
                Ps[(size_t)fl * N + kk];
        }
    };

    float acc[2][F];
#pragma unroll
    for (int rr = 0; rr < 2; ++rr)
#pragma unroll
        for (int f = 0; f < F; ++f) acc[rr][f] = 0.f;

    float4 Abuf[2][C], Bbuf[2][C];

    auto ld = [&](float4(&buf)[2][C], int g) {  // rows wrow0+2g, +2g+1: seq bursts
#pragma unroll
        for (int rr = 0; rr < 2; ++rr)
#pragma unroll
            for (int c = 0; c < C; ++c)
                buf[rr][c] = *reinterpret_cast<const float4*>(
                    Ab + (size_t)(2 * g + rr) * N + c * 256);
    };

    auto cmp = [&](auto Hc, float4(&buf)[2][C]) {
        constexpr int HALF = decltype(Hc)::value;
#pragma unroll
        for (int c = 0; c < C; ++c)
#pragma unroll
            for (int t = 0; t < 4; ++t)
#pragma unroll
                for (int g = 0; g < G2; ++g) {
                    const float4 pv = *reinterpret_cast<const float4*>(
                        &plds[(t * G2 + g) * W + (c * 64 + lane) * 4]);
#pragma unroll
                    for (int rr = 0; rr < 2; ++rr) {
                        const float av = (t == 0)   ? buf[rr][c].x
                                         : (t == 1) ? buf[rr][c].y
                                         : (t == 2) ? buf[rr][c].z
                                                    : buf[rr][c].w;
                        acc[rr][HALF * (F / 2) + g * 4 + 0] += av * pv.x;
                        acc[rr][HALF * (F / 2) + g * 4 + 1] += av * pv.y;
                        acc[rr][HALF * (F / 2) + g * 4 + 2] += av * pv.z;
                        acc[rr][HALF * (F / 2) + g * 4 + 3] += av * pv.w;
                    }
                }
    };

    auto redstore = [&](int g) {
        constexpr int NV = 2 * F;  // 32 | 64
        float v[NV];
#pragma unroll
        for (int i = 0; i < NV; ++i) v[i] = acc[i / F][i % F];
#pragma unroll
        for (int s = 0; (NV >> s) > 1; ++s) {
            const int bit = (lane >> s) & 1;
#pragma unroll
            for (int i = 0; i < (NV >> s); i += 2) {
                const float t0 = __shfl_xor(v[i], 1 << s);
                const float t1 = __shfl_xor(v[i + 1], 1 << s);
                v[i >> 1] = bit ? (v[i + 1] + t1) : (v[i] + t0);
            }
        }
        float r = v[0];
        if constexpr (NV == 32) {  // F=16: lanes l, l+32 hold same (m,f); merge
            r += __shfl_xor(r, 32);
            if (lane < 32)
                pb[((size_t)sl * N + wrow0 + 2 * g + (lane >> 4)) * F + (lane & 15)] = r;
        } else {  // F=32: lane l holds (m,f) = (l>>5, l&31)
            pb[((size_t)sl * N + wrow0 + 2 * g + (lane >> 5)) * F + (lane & 31)] = r;
        }
#pragma unroll
        for (int rr = 0; rr < 2; ++rr)
#pragma unroll
            for (int f = 0; f < F; ++f) acc[rr][f] = 0.f;
    };

    using IC0 = std::integral_constant<int, 0>;
    using IC1 = std::integral_constant<int, 1>;

    stage(0);
    ld(Abuf, 0);
    __syncthreads();
    for (int gp = 0; gp < NG; gp += 2) {
        ld(Bbuf, gp + 1);        // flies across half0 compute + staging
        cmp(IC0{}, Abuf);
        __syncthreads();
        stage(1);
        __syncthreads();
        cmp(IC1{}, Abuf);
        redstore(gp);
        if (gp + 2 < NG) ld(Abuf, gp + 2);  // flies across Bbuf compute + staging
        cmp(IC1{}, Bbuf);
        __syncthreads();
        stage(0);
        __syncthreads();
        cmp(IC0{}, Bbuf);
        redstore(gp + 1);
    }
}

// ---- split-K reduce: out = relu(bias + sum_s part[s]) ----
template <int F, int NS>
__global__ void k_reduce(const float* __restrict__ part,
                         const float* __restrict__ bias0, const float* __restrict__ bias1,
                         float* __restrict__ o0, float* __restrict__ o1, int ostride) {
    const int br = blockIdx.y;
    const float* __restrict__ pb = part + (size_t)br * NS * N * F;
    const float* __restrict__ bias = br ? bias1 : bias0;
    float* __restrict__ o = br ? o1 : o0;
    const int i = blockIdx.x * 256 + threadIdx.x;  // over N*F
    const int r = i / F, f = i % F;
    float s = bias[f];
#pragma unroll
    for (int sl = 0; sl < NS; ++sl) s += pb[(size_t)sl * N * F + i];
    o[(size_t)r * ostride + f] = fmaxf(s, 0.f);
}

// ------- kernel 5: per-block partials of Z_h = sum e^{s}, U_h = sum e^{s}(h.Wd_h)
// tanh in [-1,1] -> softmax without max-subtraction is safe.
__global__ void k_att_pool(const float* __restrict__ h, const float* __restrict__ Watt,
                           const float* __restrict__ Wd, float* __restrict__ partials) {
    __shared__ float sWa[64 * 3];
    __shared__ float sWd[192];
    for (int i = threadIdx.x; i < 192; i += blockDim.x) {
        sWa[i] = Watt[i];
        sWd[i] = Wd[i];
    }
    __syncthreads();
    const int n = blockIdx.x * blockDim.x + threadIdx.x;  // 32*256 == N exactly
    float hv[64];
#pragma unroll
    for (int q = 0; q < 16; ++q)
        *reinterpret_cast<float4*>(&hv[q * 4]) =
            *reinterpret_cast<const float4*>(&h[(size_t)n * 64 + q * 4]);
    float s0 = 0.f, s1 = 0.f, s2 = 0.f;
#pragma unroll
    for (int d = 0; d < 64; ++d) {
        s0 += hv[d] * sWa[d * 3 + 0];
        s1 += hv[d] * sWa[d * 3 + 1];
        s2 += hv[d] * sWa[d * 3 + 2];
    }
    float dot0 = 0.f, dot1 = 0.f, dot2 = 0.f;
#pragma unroll
    for (int d = 0; d < 64; ++d) {
        dot0 += hv[d] * sWd[0 * 64 + d];
        dot1 += hv[d] * sWd[1 * 64 + d];
        dot2 += hv[d] * sWd[2 * 64 + d];
    }
    const float e0 = expf(tanhf(s0));
    const float e1 = expf(tanhf(s1));
    const float e2 = expf(tanhf(s2));
    float vals[6] = {e0, e1, e2, e0 * dot0, e1 * dot1, e2 * dot2};
#pragma unroll
    for (int i = 0; i < 6; ++i) {
        float v = vals[i];
#pragma unroll
        for (int off = 1; off < 64; off <<= 1) v += __shfl_xor(v, off);
        vals[i] = v;
    }
    __shared__ float sred[4][6];
    const int wave = threadIdx.x >> 6, lane = threadIdx.x & 63;
    if (lane == 0) {
#pragma unroll
        for (int i = 0; i < 6; ++i) sred[wave][i] = vals[i];
    }
    __syncthreads();
    if (threadIdx.x == 0) {
#pragma unroll
        for (int i = 0; i < 6; ++i)
            partials[blockIdx.x * 6 + i] = sred[0][i] + sred[1][i] + sred[2][i] + sred[3][i];
    }
}

// ------------- kernel 6: out = sum_h U_h/Z_h + b_dense -------------
__global__ void k_att_final(const float* __restrict__ partials, const float* __restrict__ bd,
                            float* __restrict__ out) {
    if (threadIdx.x == 0) {
        float Z0 = 0.f, Z1 = 0.f, Z2 = 0.f, U0 = 0.f, U1 = 0.f, U2 = 0.f;
        for (int b = 0; b < 32; ++b) {
            Z0 += partials[b * 6 + 0];
            Z1 += partials[b * 6 + 1];
            Z2 += partials[b * 6 + 2];
            U0 += partials[b * 6 + 3];
            U1 += partials[b * 6 + 4];
            U2 += partials[b * 6 + 5];
        }
        out[0] = U0 / Z0 + U1 / Z1 + U2 / Z2 + bd[0];
    }
}

extern "C" void kernel_launch(void* const* d_in, const int* in_sizes, int n_in,
                              void* d_out, int out_size, void* d_ws, size_t ws_size,
                              hipStream_t stream) {
    const float* x_int   = (const float*)d_in[0];
    const float* x_nh    = (const float*)d_in[1];
    const float* adj_int = (const float*)d_in[2];
    const float* adj_nh  = (const float*)d_in[3];
    const float* W1_int  = (const float*)d_in[4];
    const float* b1_int  = (const float*)d_in[5];
    const float* W1_nh   = (const float*)d_in[6];
    const float* b1_nh   = (const float*)d_in[7];
    const float* W2_int  = (const float*)d_in[8];
    const float* b2_int  = (const float*)d_in[9];
    const float* W2_nh   = (const float*)d_in[10];
    const float* b2_nh   = (const float*)d_in[11];
    const float* W_att   = (const float*)d_in[12];
    const float* W_dense = (const float*)d_in[13];
    const float* b_dense = (const float*)d_in[14];

    float* ws = (float*)d_ws;
    float* P1T_0 = ws;                       // [16][8192]
    float* P1T_1 = ws + 131072;
    float* H1_0  = ws + 262144;              // [8192][16] row-major
    float* H1_1  = ws + 393216;
    float* P2T_0 = ws + 524288;              // [32][8192]
    float* P2T_1 = ws + 786432;
    float* hcat  = ws + 1048576;             // [8192][64] = [H2_int | H2_nh]
    float* attp  = ws + 1572864;             // [32,6]
    float* part  = ws + 1573120;             // split-K partials (16: 4MB, 32: 16MB)
    float* out = (float*)d_out;

    k_dense_in<<<dim3(32, 2), 256, 0, stream>>>(x_int, x_nh, W1_int, W1_nh, P1T_0, P1T_1);
    // F=16: NS=4, 64 row-blocks -> grid.x = 256
    k_spmm<16><<<dim3(256, 2), 512, 0, stream>>>(adj_int, adj_nh, P1T_0, P1T_1, part);
    k_reduce<16, 4><<<dim3(512, 2), 256, 0, stream>>>(part, b1_int, b1_nh, H1_0, H1_1, 16);
    k_dense_mid<<<dim3(32, 2), 256, 0, stream>>>(H1_0, H1_1, W2_int, W2_nh, P2T_0, P2T_1);
    // F=32: NS=8, 64 row-blocks -> grid.x = 512
    k_spmm<32><<<dim3(512, 2), 512, 0, stream>>>(adj_int, adj_nh, P2T_0, P2T_1, part);
    k_reduce<32, 8><<<dim3(1024, 2), 256, 0, stream>>>(part, b2_int, b2_nh, hcat, hcat + 32, 64);
    k_att_pool<<<32, 256, 0, stream>>>(hcat, W_att, W_dense, attp);
    k_att_final<<<1, 64, 0, stream>>>(attp, b_dense, out);
}